// Round 4
// baseline (255.991 us; speedup 1.0000x reference)
//
#include <hip/hip_runtime.h>
#include <math.h>

// Problem: B=64, N=4096, K=128. Labels C in [0,128).
// out[b,i,k] = (rank(C[b,i]) == k) ? u : ndtri(clip(U,1e-7,1-1e-7) * Phi(u))
// where u = mu + sigma*eps[b,i], rank = index of C[b,i] in sorted unique(C).
//
// ws[0..3]  : 128-bit presence bitmap over label values (zeroed via memset)
// ws+256    : float2 {u, Phi(u)} per row (2 MB)
// Pass 1 (row_kernel): presence bitmap + per-row u/phi  (262144 threads)
// Pass 2 (map_kernel): one thread per float4 of U; branchless fp32 Acklam
//                      ndtri; nontemporal load/store for the 256 MiB stream.

// Native clang vector for nontemporal builtins (HIP float4 is a class and
// __builtin_nontemporal_* rejects it; this alias has identical 16B layout).
typedef float vfloat4 __attribute__((ext_vector_type(4)));

// ---------------------------------------------------------------------------
// Acklam's inverse normal CDF, fp32, BRANCHLESS (both paths computed, select).
// Safe over p in [~3e-13, 1-1.19e-7]: tail poly at pm=0.5 and central poly at
// r=0.25 are both finite, so unconditional evaluation never produces NaN/Inf.
__device__ __forceinline__ float ndtri_acklam(float p) {
    const bool upper = p > 0.5f;
    const float pm = upper ? (1.0f - p) : p;   // min(p, 1-p), >= 1.19e-7

    // --- tail path: q = sqrt(-2 ln pm), valid pm in (0, 0.02425) ---
    float q = sqrtf(-2.0f * __logf(pm));
    float tn = -0.007784894002430293f;
    tn = fmaf(tn, q, -0.3223964580411365f);
    tn = fmaf(tn, q, -2.400758277161838f);
    tn = fmaf(tn, q, -2.549732539343734f);
    tn = fmaf(tn, q,  4.374664141464968f);
    tn = fmaf(tn, q,  2.938163982698783f);
    float td = 0.007784695709041462f;
    td = fmaf(td, q, 0.3224671290700398f);
    td = fmaf(td, q, 2.445134137142996f);
    td = fmaf(td, q, 3.754408661907416f);
    td = fmaf(td, q, 1.0f);
    float xt = tn * __builtin_amdgcn_rcpf(td);  // lower-tail value (negative)
    xt = upper ? -xt : xt;

    // --- central path: rational in r = (p-0.5)^2, valid pm >= 0.02425 ---
    float qc = p - 0.5f;
    float r = qc * qc;
    float cn = -39.69683028665376f;
    cn = fmaf(cn, r,  220.9460984245205f);
    cn = fmaf(cn, r, -275.9285104469687f);
    cn = fmaf(cn, r,  138.3577518672690f);
    cn = fmaf(cn, r,  -30.66479806614716f);
    cn = fmaf(cn, r,    2.506628277459239f);
    float cd = -54.47609879822406f;
    cd = fmaf(cd, r,  161.5858368580409f);
    cd = fmaf(cd, r, -155.6989798598866f);
    cd = fmaf(cd, r,   66.80131188771972f);
    cd = fmaf(cd, r,  -13.28068155288572f);
    cd = fmaf(cd, r,    1.0f);
    float xc = qc * cn * __builtin_amdgcn_rcpf(cd);

    return (pm < 0.02425f) ? xt : xc;
}

// ---------------------------------------------------------------------------
// Pass 1: presence bitmap + per-row (u, Phi(u))
__global__ void __launch_bounds__(256) row_kernel(
    const int* __restrict__ C,
    const float* __restrict__ eps,
    const float* __restrict__ mu_p,
    const float* __restrict__ sigma_p,
    unsigned* __restrict__ mask,
    float2* __restrict__ uphi,
    int n)
{
    __shared__ unsigned sm[4];
    if (threadIdx.x < 4) sm[threadIdx.x] = 0u;
    __syncthreads();

    int i = blockIdx.x * blockDim.x + threadIdx.x;
    unsigned m0 = 0, m1 = 0, m2 = 0, m3 = 0;
    if (i < n) {
        int c = C[i];
        float u = fmaf(sigma_p[0], eps[i], mu_p[0]);
        float phi = 0.5f * erfcf(-u * 0.7071067811865476f);
        uphi[i] = make_float2(u, phi);
        unsigned bit = 1u << (c & 31);
        int w = (c >> 5) & 3;
        m0 = (w == 0) ? bit : 0u;
        m1 = (w == 1) ? bit : 0u;
        m2 = (w == 2) ? bit : 0u;
        m3 = (w == 3) ? bit : 0u;
    }
    #pragma unroll
    for (int off = 32; off > 0; off >>= 1) {
        m0 |= __shfl_down(m0, off, 64);
        m1 |= __shfl_down(m1, off, 64);
        m2 |= __shfl_down(m2, off, 64);
        m3 |= __shfl_down(m3, off, 64);
    }
    if ((threadIdx.x & 63) == 0) {
        if (m0) atomicOr(&sm[0], m0);
        if (m1) atomicOr(&sm[1], m1);
        if (m2) atomicOr(&sm[2], m2);
        if (m3) atomicOr(&sm[3], m3);
    }
    __syncthreads();
    if (threadIdx.x < 4) {
        unsigned v = sm[threadIdx.x];
        if (v) atomicOr(&mask[threadIdx.x], v);
    }
}

// ---------------------------------------------------------------------------
// Pass 2: one thread per float4 (4 consecutive k of one row)
__global__ void __launch_bounds__(256) map_kernel(
    const int* __restrict__ C,
    const vfloat4* __restrict__ U4,
    const float2* __restrict__ uphi,
    const unsigned* __restrict__ mask,
    vfloat4* __restrict__ out4,
    int total4)
{
    int idx = blockIdx.x * blockDim.x + threadIdx.x;
    if (idx >= total4) return;
    int row = idx >> 5;        // K/4 = 32 float4 per row
    int k0  = (idx & 31) << 2;

    // Issue the streaming load first so it's in flight during rank/phi calc.
    vfloat4 Uv = __builtin_nontemporal_load(&U4[idx]);

    float2 up = uphi[row];
    float u = up.x;
    float phi = up.y;

    // rank = popcount of presence bits strictly below c
    int c = C[row];
    unsigned w0 = mask[0], w1 = mask[1], w2 = mask[2], w3 = mask[3];
    int cw = c >> 5;
    unsigned below = (1u << (c & 31)) - 1u;
    int rank = __popc(w0 & ((0 < cw) ? 0xFFFFFFFFu : ((0 == cw) ? below : 0u)))
             + __popc(w1 & ((1 < cw) ? 0xFFFFFFFFu : ((1 == cw) ? below : 0u)))
             + __popc(w2 & ((2 < cw) ? 0xFFFFFFFFu : ((2 == cw) ? below : 0u)))
             + __popc(w3 & ((3 < cw) ? 0xFFFFFFFFu : ((3 == cw) ? below : 0u)));

    const float lo = 1e-7f;
    const float hi = 0.99999988079071045f;  // fp32(1 - 1e-7), matches jnp.clip

    float p0 = fminf(fmaxf(Uv.x, lo), hi) * phi;
    float p1 = fminf(fmaxf(Uv.y, lo), hi) * phi;
    float p2 = fminf(fmaxf(Uv.z, lo), hi) * phi;
    float p3 = fminf(fmaxf(Uv.w, lo), hi) * phi;

    float z0 = ndtri_acklam(p0);
    float z1 = ndtri_acklam(p1);
    float z2 = ndtri_acklam(p2);
    float z3 = ndtri_acklam(p3);

    vfloat4 o;
    o.x = (k0 + 0 == rank) ? u : z0;
    o.y = (k0 + 1 == rank) ? u : z1;
    o.z = (k0 + 2 == rank) ? u : z2;
    o.w = (k0 + 3 == rank) ? u : z3;
    __builtin_nontemporal_store(o, &out4[idx]);
}

extern "C" void kernel_launch(void* const* d_in, const int* in_sizes, int n_in,
                              void* d_out, int out_size, void* d_ws, size_t ws_size,
                              hipStream_t stream) {
    const int*   C     = (const int*)d_in[0];
    const float* eps   = (const float*)d_in[1];
    const vfloat4* U4  = (const vfloat4*)d_in[2];
    const float* mu    = (const float*)d_in[3];
    const float* sigma = (const float*)d_in[4];
    vfloat4* out4 = (vfloat4*)d_out;

    unsigned* mask = (unsigned*)d_ws;
    float2* uphi = (float2*)((char*)d_ws + 256);

    int n = in_sizes[0];           // B*N = 262144 rows
    int total4 = out_size / 4;     // 8388608 float4s

    // ws is re-poisoned to 0xAA before every timed launch — zero the bitmap.
    (void)hipMemsetAsync(d_ws, 0, 4 * sizeof(unsigned), stream);

    int rb = (n + 255) / 256;
    row_kernel<<<rb, 256, 0, stream>>>(C, eps, mu, sigma, mask, uphi, n);

    int mb = (total4 + 255) / 256;
    map_kernel<<<mb, 256, 0, stream>>>(C, U4, uphi, mask, out4, total4);
}